// Round 1
// baseline (221.928 us; speedup 1.0000x reference)
//
#include <hip/hip_runtime.h>
#include <hip/hip_bf16.h>

typedef __attribute__((ext_vector_type(8))) short bf16x8;
typedef __attribute__((ext_vector_type(4))) float f32x4;

constexpr int BROWS = 131072;
constexpr int DDIM  = 128;

__device__ __forceinline__ short to_bf16(float f) {
    unsigned u = __builtin_bit_cast(unsigned, f);
    u = (u + 0x7FFFu + ((u >> 16) & 1u)) >> 16;   // RTNE
    return (short)u;
}

__device__ __forceinline__ bf16x8 cvt8(const float* __restrict__ p) {
    f32x4 lo = *reinterpret_cast<const f32x4*>(p);
    f32x4 hi = *reinterpret_cast<const f32x4*>(p + 4);
    bf16x8 r;
#pragma unroll
    for (int i = 0; i < 4; ++i) { r[i] = to_bf16(lo[i]); r[i + 4] = to_bf16(hi[i]); }
    return r;
}

__global__ void __launch_bounds__(256)
lfm_kernel(const float* __restrict__ state, const float* __restrict__ W,
           const float* __restrict__ bias, float* __restrict__ out) {
    const int lane = threadIdx.x & 63;
    const int wave = threadIdx.x >> 6;
    const int l16  = lane & 15;
    const int lq   = lane >> 4;

    // ---- W fragments: this wave owns global cols [wave*64, wave*64+64) ----
    // col c -> n = c&127, o = c>>7 ; W row (length 128) at W + n*256 + o*128.
    // B-frag layout: col = lane&15, k = lq*8 + j (8 contiguous k per lane).
    const int colbase = wave * 64;
    bf16x8 wfrag[4][4];     // [col-tile][k-step] -- static-indexed (fully unrolled)
    float  biasr[4];
#pragma unroll
    for (int ct = 0; ct < 4; ++ct) {
        const int c = colbase + ct * 16 + l16;
        const int n = c & 127, o = c >> 7;
        const float* wrow = W + n * 256 + o * 128;
        biasr[ct] = bias[n * 2 + o];
#pragma unroll
        for (int ks = 0; ks < 4; ++ks)
            wfrag[ct][ks] = cvt8(wrow + ks * 32 + lq * 8);
    }

    const int ntiles = BROWS / 16;   // 8192 row-tiles of 16
    for (int t = blockIdx.x; t < ntiles; t += gridDim.x) {
        // ---- A fragments: 16 rows x 128 k, lane reads 8 contiguous fp32/k-step
        const float* srow = state + (size_t)(t * 16 + l16) * DDIM;
        bf16x8 afrag[4];
#pragma unroll
        for (int ks = 0; ks < 4; ++ks)
            afrag[ks] = cvt8(srow + ks * 32 + lq * 8);

#pragma unroll
        for (int ct = 0; ct < 4; ++ct) {
            f32x4 acc = { biasr[ct], biasr[ct], biasr[ct], biasr[ct] };
#pragma unroll
            for (int ks = 0; ks < 4; ++ks)
                acc = __builtin_amdgcn_mfma_f32_16x16x32_bf16(
                        afrag[ks], wfrag[ct][ks], acc, 0, 0, 0);

            // C/D layout: col = lane&15, row = lq*4 + reg   [m89/m91 verified]
            const int c = colbase + ct * 16 + l16;
            const size_t row = (size_t)t * 16 + lq * 4;
            float* dst = out + ((c < 128)
                                ? (row * 128 + c)
                                : ((size_t)BROWS * 128 + row * 128 + (c - 128)));
#pragma unroll
            for (int r = 0; r < 4; ++r)
                dst[(size_t)r * 128] = acc[r];
        }
    }
}

extern "C" void kernel_launch(void* const* d_in, const int* in_sizes, int n_in,
                              void* d_out, int out_size, void* d_ws, size_t ws_size,
                              hipStream_t stream) {
    const float* state = (const float*)d_in[0];
    const float* W     = (const float*)d_in[1];
    const float* bias  = (const float*)d_in[2];
    float* out = (float*)d_out;
    hipLaunchKernelGGL(lfm_kernel, dim3(2048), dim3(256), 0, stream,
                       state, W, bias, out);
}